// Round 4
// baseline (206.893 us; speedup 1.0000x reference)
//
#include <hip/hip_runtime.h>

// Two-phase EdgeNetwork, atomic-free output:
//  P1: bucket edges by src (cnt + slots, int atomics only).
//  P2: transformed[e] = (bond@K+bias).reshape(32,32) @ atom[nbr]  via MFMA,
//      stored f16, coalesced (no atomics).
//  P3: out[a] = sum over slots[a] of transformed rows (coalesced gather).

typedef _Float16 half8 __attribute__((ext_vector_type(8)));
typedef float float4v __attribute__((ext_vector_type(4)));

constexpr int NA = 100000;
constexpr int E = 400000;
constexpr int TILES = E / 32;      // 12500 tiles of 32 edges
constexpr int NBLK = 1536;
constexpr int WAVES = NBLK * 4;
constexpr int HALFW = WAVES / 2;   // waves per column-half
constexpr int MAXDEG = 32;         // P(Poisson(4) > 32) ~ 1e-19 per atom

// ws layout (bytes)
constexpr size_t OFF_CNT   = 0;                       // int[NA]
constexpr size_t OFF_SLOTS = 400000;                  // int[NA*MAXDEG]
constexpr size_t OFF_T     = OFF_SLOTS + (size_t)NA * MAXDEG * 4;  // _Float16[E*32]

__global__ void k_zero(int* __restrict__ cnt) {
  int i = blockIdx.x * blockDim.x + threadIdx.x;
  if (i < NA) cnt[i] = 0;
}

__global__ void k_place(const int* __restrict__ pairs,
                        int* __restrict__ cnt, int* __restrict__ slots) {
  int e = blockIdx.x * blockDim.x + threadIdx.x;
  if (e < E) {
    const int s = ((const int2*)pairs)[e].x;
    int p = atomicAdd(&cnt[s], 1);
    p = min(p, MAXDEG - 1);          // memory safety; never hit in practice
    slots[s * MAXDEG + p] = e;
  }
}

static __device__ inline half8 splat8(_Float16 v) {
  half8 r = {v, v, v, v, v, v, v, v};
  return r;
}

__global__ __launch_bounds__(256, 4)
void k_transform(const float* __restrict__ atom,
                 const float* __restrict__ bondf,
                 const int* __restrict__ pairs,
                 const float* __restrict__ Kmat,
                 const float* __restrict__ bias,
                 _Float16* __restrict__ T)
{
  const int tid   = threadIdx.x;
  const int lane  = tid & 63;
  const int wslot = tid >> 6;
  const int wid   = blockIdx.x * 4 + wslot;
  const int h     = wid & 1;                  // column half this wave owns
  const int q     = lane >> 4;
  const int el    = lane & 15;
  const int n     = el + h * 16;              // output column
  const int j0    = q * 8;

  // B-fragments for all 17 K-steps in registers.
  half8 Wr[17];
  #pragma unroll
  for (int s = 0; s < 17; ++s) {
    const float* src = (s < 16) ? (Kmat + s * 1024 + n * 32 + j0)
                                : (bias + n * 32 + j0);
    half8 w;
    #pragma unroll
    for (int j = 0; j < 8; ++j) w[j] = (_Float16)src[j];
    Wr[s] = w;
  }

  for (int tile = (wid >> 1); tile < TILES; tile += HALFW) {
    const int ebase = tile * 32;

    // lanes 0..31 load nbr of edge ebase+lane; broadcast via shuffle.
    int pv = 0;
    if (lane < 32) pv = pairs[2 * (ebase + lane) + 1];
    const int aA = __shfl(pv, el);
    const int aB = __shfl(pv, el + 16);

    half8 nbA, nbB;
    {
      const float* pa = atom + (size_t)aA * 32 + j0;
      const float* pb = atom + (size_t)aB * 32 + j0;
      #pragma unroll
      for (int j = 0; j < 8; ++j) {
        nbA[j] = (_Float16)pa[j];
        nbB[j] = (_Float16)pb[j];
      }
    }
    _Float16 bA[16], bB[16];
    {
      const float* ba = bondf + (size_t)(ebase + el) * 16;
      const float* bb = bondf + (size_t)(ebase + el + 16) * 16;
      #pragma unroll
      for (int b = 0; b < 16; ++b) {
        bA[b] = (_Float16)ba[b];
        bB[b] = (_Float16)bb[b];
      }
    }

    float4v acc0 = {0.f, 0.f, 0.f, 0.f};
    float4v acc1 = {0.f, 0.f, 0.f, 0.f};
    #pragma unroll
    for (int s = 0; s < 16; ++s) {
      const half8 aAf = nbA * splat8(bA[s]);
      const half8 aBf = nbB * splat8(bB[s]);
      acc0 = __builtin_amdgcn_mfma_f32_16x16x32_f16(aAf, Wr[s], acc0, 0, 0, 0);
      acc1 = __builtin_amdgcn_mfma_f32_16x16x32_f16(aBf, Wr[s], acc1, 0, 0, 0);
    }
    acc0 = __builtin_amdgcn_mfma_f32_16x16x32_f16(nbA, Wr[16], acc0, 0, 0, 0);
    acc1 = __builtin_amdgcn_mfma_f32_16x16x32_f16(nbB, Wr[16], acc1, 0, 0, 0);

    // Store C rows: edge m = q*4 + r, col n. Plain f16 stores, no atomics.
    #pragma unroll
    for (int r = 0; r < 4; ++r) {
      const int e0 = ebase + q * 4 + r;
      T[(size_t)e0 * 32 + n] = (_Float16)acc0[r];
      const int e1 = e0 + 16;
      T[(size_t)e1 * 32 + n] = (_Float16)acc1[r];
    }
  }
}

__global__ __launch_bounds__(256)
void k_reduce(const int* __restrict__ cnt, const int* __restrict__ slots,
              const _Float16* __restrict__ T, float* __restrict__ out) {
  const int tid = blockIdx.x * blockDim.x + threadIdx.x;
  const int a = tid >> 5;          // atom
  const int c = tid & 31;          // column
  if (a >= NA) return;
  const int d = min(cnt[a], MAXDEG);
  const int* row = slots + (size_t)a * MAXDEG;
  float sum = 0.f;
  for (int p = 0; p < d; ++p) {
    const int e = row[p];          // uniform across the 32 col-lanes
    sum += (float)T[(size_t)e * 32 + c];   // 64 B contiguous line per edge
  }
  out[(size_t)a * 32 + c] = sum;
}

extern "C" void kernel_launch(void* const* d_in, const int* in_sizes, int n_in,
                              void* d_out, int out_size, void* d_ws, size_t ws_size,
                              hipStream_t stream) {
  const float* atom  = (const float*)d_in[0];   // (100000, 32) f32
  const float* bondf = (const float*)d_in[1];   // (400000, 16) f32
  const int*   pairs = (const int*)d_in[2];     // (400000, 2) int32
  const float* Kmat  = (const float*)d_in[3];   // (16, 1024) f32
  const float* bias  = (const float*)d_in[4];   // (1024,) f32
  float* out = (float*)d_out;                   // (100000, 32) f32

  int* cnt        = (int*)((char*)d_ws + OFF_CNT);
  int* slots      = (int*)((char*)d_ws + OFF_SLOTS);
  _Float16* T     = (_Float16*)((char*)d_ws + OFF_T);

  k_zero<<<(NA + 255) / 256, 256, 0, stream>>>(cnt);
  k_place<<<(E + 255) / 256, 256, 0, stream>>>(pairs, cnt, slots);
  k_transform<<<NBLK, 256, 0, stream>>>(atom, bondf, pairs, Kmat, bias, T);
  k_reduce<<<(NA * 32 + 255) / 256, 256, 0, stream>>>(cnt, slots, T, out);
}

// Round 5
// 139.836 us; speedup vs baseline: 1.4795x; 1.4795x over previous
//
#include <hip/hip_runtime.h>

// Fused EdgeNetwork, 2-deep software-pipelined persistent waves.
//   OUT = P @ W on MFMA:  P[e, b*32+j] = bond[e,b]*nb[e,j]  (b=16 -> bias row)
//   W[b*32+j, i] = K[b, i*32+j]  held in 68 VGPRs per wave (col-half split).
// Pipeline: while tile t computes its MFMA chain, tile t+1's atom-row gathers
// (data-dependent) are in flight and tile t+2's pair indices are loading.
// k_prep pre-converts atom/bond to f16 in ws and zeroes out.

typedef _Float16 half8 __attribute__((ext_vector_type(8)));
typedef _Float16 half4t __attribute__((ext_vector_type(4)));
typedef float float4v __attribute__((ext_vector_type(4)));

constexpr int NA = 100000;
constexpr int E  = 400000;
constexpr int TILES = E / 32;          // 12500
constexpr int NBLK  = 768;             // 3 blocks/CU
constexpr int HALFW = NBLK * 4 / 2;    // 1536 waves per column-half

constexpr size_t OFF_ATOMH = 0;                  // _Float16[NA*32]  (6.4 MB)
constexpr size_t OFF_BONDH = (size_t)NA * 32 * 2; // _Float16[E*16] (12.8 MB)

constexpr int NZ4 = NA * 32 / 4;   // out zeroing, float4 units
constexpr int NA4 = NA * 32 / 4;   // atom convert, float4 units
constexpr int NB4 = E * 16 / 4;    // bond convert, float4 units
constexpr int PREP_TOT = NZ4 + NA4 + NB4;

__global__ void k_prep(const float* __restrict__ atom,
                       const float* __restrict__ bond,
                       float4* __restrict__ outz,
                       half4t* __restrict__ atomh4,
                       half4t* __restrict__ bondh4) {
  int i = blockIdx.x * blockDim.x + threadIdx.x;
  if (i < NZ4) {
    outz[i] = make_float4(0.f, 0.f, 0.f, 0.f);
  } else if (i < NZ4 + NA4) {
    int k = i - NZ4;
    float4 v = ((const float4*)atom)[k];
    half4t hh = { (_Float16)v.x, (_Float16)v.y, (_Float16)v.z, (_Float16)v.w };
    atomh4[k] = hh;
  } else if (i < PREP_TOT) {
    int k = i - NZ4 - NA4;
    float4 v = ((const float4*)bond)[k];
    half4t hh = { (_Float16)v.x, (_Float16)v.y, (_Float16)v.z, (_Float16)v.w };
    bondh4[k] = hh;
  }
}

static __device__ inline half8 splat8(_Float16 v) {
  half8 r = {v, v, v, v, v, v, v, v};
  return r;
}

__global__ __launch_bounds__(256, 3)
void edge_fused(const _Float16* __restrict__ atomh,
                const _Float16* __restrict__ bondh,
                const int* __restrict__ pairs,
                const float* __restrict__ Kmat,
                const float* __restrict__ bias,
                float* __restrict__ out)
{
  const int tid  = threadIdx.x;
  const int lane = tid & 63;
  const int wid  = blockIdx.x * 4 + (tid >> 6);
  const int h    = wid & 1;          // column half this wave owns
  const int q    = lane >> 4;
  const int el   = lane & 15;
  const int n    = el + h * 16;      // output column
  const int j0   = q * 8;

  // W fragments for all 17 K-steps, register-resident.
  half8 Wr[17];
  #pragma unroll
  for (int s = 0; s < 17; ++s) {
    const float* src = (s < 16) ? (Kmat + s * 1024 + n * 32 + j0)
                                : (bias + n * 32 + j0);
    half8 w;
    #pragma unroll
    for (int j = 0; j < 8; ++j) w[j] = (_Float16)src[j];
    Wr[s] = w;
  }

  const int start  = wid >> 1;
  const int stride = HALFW;
  const int2* pairs2 = (const int2*)pairs;

  auto ldpv = [&](int t) -> int2 {
    const int tc = t < TILES ? t : TILES - 1;   // clamp: loads stay valid
    int2 v = make_int2(0, 0);
    if (lane < 32) v = pairs2[tc * 32 + lane];
    return v;
  };

  // ---- Pipeline prologue: stage tile `start`, start indices for start+stride.
  int2 pv0 = ldpv(start);
  int2 pv1 = ldpv(start + stride);

  half8 nbA_c, nbB_c, bA0_c, bA1_c, bB0_c, bB1_c;
  {
    const int aA = __shfl(pv0.y, el);
    const int aB = __shfl(pv0.y, el + 16);
    nbA_c = *(const half8*)(atomh + (size_t)aA * 32 + j0);
    nbB_c = *(const half8*)(atomh + (size_t)aB * 32 + j0);
    const _Float16* brA = bondh + (size_t)(start * 32 + el) * 16;
    const _Float16* brB = bondh + (size_t)(start * 32 + el + 16) * 16;
    bA0_c = *(const half8*)(brA);  bA1_c = *(const half8*)(brA + 8);
    bB0_c = *(const half8*)(brB);  bB1_c = *(const half8*)(brB + 8);
  }

  for (int t = start; t < TILES; t += stride) {
    const int tn = t + stride;

    // ---- Stage next tile first (loads in flight across this tile's compute).
    half8 nbA_n, nbB_n, bA0_n, bA1_n, bB0_n, bB1_n;
    {
      const int aA = __shfl(pv1.y, el);
      const int aB = __shfl(pv1.y, el + 16);
      nbA_n = *(const half8*)(atomh + (size_t)aA * 32 + j0);
      nbB_n = *(const half8*)(atomh + (size_t)aB * 32 + j0);
      const int tc = tn < TILES ? tn : TILES - 1;
      const _Float16* brA = bondh + (size_t)(tc * 32 + el) * 16;
      const _Float16* brB = bondh + (size_t)(tc * 32 + el + 16) * 16;
      bA0_n = *(const half8*)(brA);  bA1_n = *(const half8*)(brA + 8);
      bB0_n = *(const half8*)(brB);  bB1_n = *(const half8*)(brB + 8);
    }
    const int2 pv2 = ldpv(tn + stride);

    // ---- Compute current tile.
    float4v acc0 = {0.f, 0.f, 0.f, 0.f};
    float4v acc1 = {0.f, 0.f, 0.f, 0.f};
    #pragma unroll
    for (int s = 0; s < 16; ++s) {
      const _Float16 sA = (s < 8) ? bA0_c[s] : bA1_c[s - 8];
      const _Float16 sB = (s < 8) ? bB0_c[s] : bB1_c[s - 8];
      const half8 aAf = nbA_c * splat8(sA);
      const half8 aBf = nbB_c * splat8(sB);
      acc0 = __builtin_amdgcn_mfma_f32_16x16x32_f16(aAf, Wr[s], acc0, 0, 0, 0);
      acc1 = __builtin_amdgcn_mfma_f32_16x16x32_f16(aBf, Wr[s], acc1, 0, 0, 0);
    }
    acc0 = __builtin_amdgcn_mfma_f32_16x16x32_f16(nbA_c, Wr[16], acc0, 0, 0, 0);
    acc1 = __builtin_amdgcn_mfma_f32_16x16x32_f16(nbB_c, Wr[16], acc1, 0, 0, 0);

    // ---- Epilogue: fire-and-forget atomics for current tile.
    #pragma unroll
    for (int r = 0; r < 4; ++r) {
      const int s0 = __shfl(pv0.x, q * 4 + r);
      atomicAdd(out + (size_t)s0 * 32 + n, acc0[r]);
      const int s1 = __shfl(pv0.x, q * 4 + r + 16);
      atomicAdd(out + (size_t)s1 * 32 + n, acc1[r]);
    }

    // ---- Rotate pipeline registers.
    pv0 = pv1; pv1 = pv2;
    nbA_c = nbA_n; nbB_c = nbB_n;
    bA0_c = bA0_n; bA1_c = bA1_n; bB0_c = bB0_n; bB1_c = bB1_n;
  }
}

extern "C" void kernel_launch(void* const* d_in, const int* in_sizes, int n_in,
                              void* d_out, int out_size, void* d_ws, size_t ws_size,
                              hipStream_t stream) {
  const float* atom  = (const float*)d_in[0];   // (100000, 32) f32
  const float* bondf = (const float*)d_in[1];   // (400000, 16) f32
  const int*   pairs = (const int*)d_in[2];     // (400000, 2) int32
  const float* Kmat  = (const float*)d_in[3];   // (16, 1024) f32
  const float* bias  = (const float*)d_in[4];   // (1024,) f32
  float* out = (float*)d_out;                   // (100000, 32) f32

  _Float16* atomh = (_Float16*)((char*)d_ws + OFF_ATOMH);
  _Float16* bondh = (_Float16*)((char*)d_ws + OFF_BONDH);

  k_prep<<<(PREP_TOT + 255) / 256, 256, 0, stream>>>(
      atom, bondf, (float4*)out, (half4t*)atomh, (half4t*)bondh);
  edge_fused<<<NBLK, 256, 0, stream>>>(atomh, bondh, pairs, Kmat, bias, out);
}